// Round 1
// baseline (487.175 us; speedup 1.0000x reference)
//
#include <hip/hip_runtime.h>
#include <hip/hip_bf16.h>
#include <hip/hip_fp16.h>

typedef __attribute__((ext_vector_type(8))) _Float16 half8;
typedef __attribute__((ext_vector_type(4))) float f32x4;

#define N_B 8
#define C_DIM 256
#define S_DIM 4096

__device__ __forceinline__ _Float16 f2h(float f) { return (_Float16)f; }

__device__ __forceinline__ f32x4 mfma16(half8 a, half8 b, f32x4 c) {
  return __builtin_amdgcn_mfma_f32_16x16x32_f16(a, b, c, 0, 0, 0);
}

// ---- K0: transpose x (n,C,S) fp32 -> xT (n,S,C) fp16 ----
__global__ __launch_bounds__(256) void k_transpose(const float* __restrict__ x,
                                                   _Float16* __restrict__ xT) {
  __shared__ _Float16 tile[64][65];
  int n = blockIdx.z, cb = blockIdx.y * 64, sb = blockIdx.x * 64;
  const float* xp = x + ((size_t)n * C_DIM + cb) * S_DIM + sb;
  int t = threadIdx.x;
#pragma unroll
  for (int p = 0; p < 4; ++p) {
    int row = p * 16 + (t >> 4);
    int col = (t & 15) * 4;
    float4 v4 = *(const float4*)(xp + (size_t)row * S_DIM + col);
    tile[row][col + 0] = f2h(v4.x);
    tile[row][col + 1] = f2h(v4.y);
    tile[row][col + 2] = f2h(v4.z);
    tile[row][col + 3] = f2h(v4.w);
  }
  __syncthreads();
  _Float16* op = xT + ((size_t)n * S_DIM + sb) * C_DIM + cb;
#pragma unroll
  for (int p = 0; p < 2; ++p) {
    int srow = p * 32 + (t >> 3);
    int ccol = (t & 7) * 8;
    half8 u;
#pragma unroll
    for (int i = 0; i < 8; ++i) u[i] = tile[ccol + i][srow];
    *(half8*)(op + (size_t)srow * C_DIM + ccol) = u;
  }
}

// ---- K0b: weights fp32 -> fp16 (Wq,Wk,Wv,Wl concatenated) ----
__global__ __launch_bounds__(256) void k_wconv(const float* __restrict__ w0, const float* __restrict__ w1,
                                               const float* __restrict__ w2, const float* __restrict__ w3,
                                               _Float16* __restrict__ Wh) {
  int idx = blockIdx.x * 256 + threadIdx.x;  // 16384 threads
  const float* srcs[4] = {w0, w1, w2, w3};
#pragma unroll
  for (int j = 0; j < 4; ++j) {
    const float* s = srcs[j];
    for (int i = idx; i < C_DIM * C_DIM; i += 16384) Wh[j * C_DIM * C_DIM + i] = f2h(s[i]);
  }
}

// ---- K1: the four projection GEMMs (NT, K=256), 128x128 tiles ----
// j=0: qT[s][o]  j=1: kT[s][o]  j=2: v[o][t] fp16  j=3: residual -> d_out fp32
__global__ __launch_bounds__(256) void k_proj(const _Float16* __restrict__ xT, const _Float16* __restrict__ Wh,
                                              _Float16* __restrict__ qT, _Float16* __restrict__ kT,
                                              _Float16* __restrict__ vv, float* __restrict__ outp) {
  __shared__ __align__(16) _Float16 As[128][72];
  __shared__ __align__(16) _Float16 Bs[128][72];
  int job = blockIdx.y;
  int n = job >> 2, j = job & 3;
  const _Float16* A;
  const _Float16* B;
  int tm, tn, ldo;
  _Float16* obf = nullptr;
  float* of32 = nullptr;
  const _Float16* xTn = xT + (size_t)n * S_DIM * C_DIM;
  if (j < 2) {
    A = xTn;
    B = Wh + j * C_DIM * C_DIM;
    tm = blockIdx.x >> 1; tn = blockIdx.x & 1;
    obf = (j == 0 ? qT : kT) + (size_t)n * S_DIM * C_DIM;
    ldo = C_DIM;
  } else {
    A = Wh + j * C_DIM * C_DIM;
    B = xTn;
    tm = blockIdx.x >> 5; tn = blockIdx.x & 31;
    ldo = S_DIM;
    if (j == 2) obf = vv + (size_t)n * C_DIM * S_DIM;
    else of32 = outp + (size_t)n * C_DIM * S_DIM;
  }
  int t = threadIdx.x, w = t >> 6, lane = t & 63, r = lane & 15, q = lane >> 4;
  int wm = w >> 1, wn = w & 1;
  f32x4 acc[4][4] = {};
  for (int kc = 0; kc < 4; ++kc) {
#pragma unroll
    for (int p = 0; p < 4; ++p) {
      int row = p * 32 + (t >> 3), c8 = (t & 7) * 8;
      *(half8*)&As[row][c8] = *(const half8*)(A + (size_t)(tm * 128 + row) * C_DIM + kc * 64 + c8);
      *(half8*)&Bs[row][c8] = *(const half8*)(B + (size_t)(tn * 128 + row) * C_DIM + kc * 64 + c8);
    }
    __syncthreads();
#pragma unroll
    for (int kk = 0; kk < 2; ++kk) {
      half8 a[4], b[4];
#pragma unroll
      for (int mi = 0; mi < 4; ++mi) a[mi] = *(const half8*)&As[wm * 64 + mi * 16 + r][kk * 32 + q * 8];
#pragma unroll
      for (int ni = 0; ni < 4; ++ni) b[ni] = *(const half8*)&Bs[wn * 64 + ni * 16 + r][kk * 32 + q * 8];
#pragma unroll
      for (int mi = 0; mi < 4; ++mi)
#pragma unroll
        for (int ni = 0; ni < 4; ++ni)
          acc[mi][ni] = mfma16(a[mi], b[ni], acc[mi][ni]);
    }
    __syncthreads();
  }
#pragma unroll
  for (int mi = 0; mi < 4; ++mi)
#pragma unroll
    for (int ni = 0; ni < 4; ++ni)
#pragma unroll
      for (int jj = 0; jj < 4; ++jj) {
        int row = tm * 128 + wm * 64 + mi * 16 + q * 4 + jj;
        int col = tn * 128 + wn * 64 + ni * 16 + r;
        float val = acc[mi][ni][jj];
        if (obf) obf[(size_t)row * ldo + col] = f2h(val);
        else of32[(size_t)row * ldo + col] = val;
      }
}

// ---- K2: row sums  l[n][t] = sum_s exp(score[t][s]) ----
// block: n = bid%8 (XCD-pinned), 128 t-rows; loops all s in chunks of 64
__global__ __launch_bounds__(512) void k_rowsum(const _Float16* __restrict__ qT, const _Float16* __restrict__ kT,
                                                float* __restrict__ lsum) {
  __shared__ __align__(16) _Float16 Ks[128][264];
  __shared__ __align__(16) _Float16 Qs[64][264];
  int bid = blockIdx.x;
  int n = bid & 7, tb = bid >> 3;
  int t = threadIdx.x, w = t >> 6, lane = t & 63, r = lane & 15, q = lane >> 4;
  const _Float16* kp = kT + (size_t)n * S_DIM * C_DIM + (size_t)tb * 128 * C_DIM;
  const _Float16* qp = qT + (size_t)n * S_DIM * C_DIM;
#pragma unroll
  for (int p = 0; p < 8; ++p) {
    int row = p * 16 + (t >> 5), c8 = (t & 31) * 8;
    *(half8*)&Ks[row][c8] = *(const half8*)(kp + (size_t)row * C_DIM + c8);
  }
  __syncthreads();
  float sumreg = 0.f;
  for (int sc = 0; sc < 64; ++sc) {
#pragma unroll
    for (int p = 0; p < 4; ++p) {
      int row = p * 16 + (t >> 5), c8 = (t & 31) * 8;
      *(half8*)&Qs[row][c8] = *(const half8*)(qp + (size_t)(sc * 64 + row) * C_DIM + c8);
    }
    __syncthreads();
    f32x4 acc[4] = {};
#pragma unroll
    for (int k = 0; k < 8; ++k) {
      half8 b = *(const half8*)&Ks[w * 16 + r][k * 32 + q * 8];
#pragma unroll
      for (int mi = 0; mi < 4; ++mi) {
        half8 a = *(const half8*)&Qs[mi * 16 + r][k * 32 + q * 8];
        acc[mi] = mfma16(a, b, acc[mi]);
      }
    }
#pragma unroll
    for (int mi = 0; mi < 4; ++mi)
#pragma unroll
      for (int jj = 0; jj < 4; ++jj) sumreg += __expf(acc[mi][jj]);
    __syncthreads();
  }
  sumreg += __shfl_xor(sumreg, 16);
  sumreg += __shfl_xor(sumreg, 32);
  if (lane < 16) lsum[n * S_DIM + tb * 128 + w * 16 + lane] = sumreg;
}

// ---- K3: attention O = V*P (recompute scores, P=exp(A)/l), += into d_out ----
// block: n = bid%8 (XCD-pinned), 64 s-cols; loops all t in chunks of 64
__global__ __launch_bounds__(512) void k_attn(const _Float16* __restrict__ qT, const _Float16* __restrict__ kT,
                                              const _Float16* __restrict__ vv, const float* __restrict__ lsum,
                                              float* __restrict__ outp) {
  __shared__ __align__(16) _Float16 Qs[64][264];
  __shared__ __align__(16) _Float16 Ks[64][264];
  __shared__ __align__(16) _Float16 Vs[256][72];
  __shared__ __align__(16) _Float16 Ps[64][72];
  __shared__ float Rs[64];
  int bid = blockIdx.x;
  int n = bid & 7, sb = bid >> 3;
  int t = threadIdx.x, w = t >> 6, lane = t & 63, r = lane & 15, q = lane >> 4;
  int ws_ = w >> 2, wt = w & 3;
  const _Float16* qp = qT + (size_t)n * S_DIM * C_DIM + (size_t)sb * 64 * C_DIM;
  const _Float16* kp0 = kT + (size_t)n * S_DIM * C_DIM;
  const _Float16* vp0 = vv + (size_t)n * C_DIM * S_DIM;
#pragma unroll
  for (int p = 0; p < 4; ++p) {
    int row = p * 16 + (t >> 5), c8 = (t & 31) * 8;
    *(half8*)&Qs[row][c8] = *(const half8*)(qp + (size_t)row * C_DIM + c8);
  }
  f32x4 acc[2][4] = {};
  __syncthreads();
  for (int tc = 0; tc < 64; ++tc) {
#pragma unroll
    for (int p = 0; p < 4; ++p) {
      int row = p * 16 + (t >> 5), c8 = (t & 31) * 8;
      *(half8*)&Ks[row][c8] = *(const half8*)(kp0 + (size_t)(tc * 64 + row) * C_DIM + c8);
    }
#pragma unroll
    for (int p = 0; p < 4; ++p) {
      int row = p * 64 + (t >> 3), c8 = (t & 7) * 8;
      *(half8*)&Vs[row][c8] = *(const half8*)(vp0 + (size_t)row * S_DIM + tc * 64 + c8);
    }
    if (t < 64) Rs[t] = 1.0f / lsum[n * S_DIM + tc * 64 + t];
    __syncthreads();
    // scores^T tile (s rows x t cols): pacc[mi] row s = ws_*32+mi*16+q*4+jj, col t = wt*16+r
    f32x4 pacc[2] = {};
#pragma unroll
    for (int k = 0; k < 8; ++k) {
      half8 b = *(const half8*)&Ks[wt * 16 + r][k * 32 + q * 8];
#pragma unroll
      for (int mi = 0; mi < 2; ++mi) {
        half8 a = *(const half8*)&Qs[ws_ * 32 + mi * 16 + r][k * 32 + q * 8];
        pacc[mi] = mfma16(a, b, pacc[mi]);
      }
    }
    float rv = Rs[wt * 16 + r];
#pragma unroll
    for (int mi = 0; mi < 2; ++mi)
#pragma unroll
      for (int jj = 0; jj < 4; ++jj) {
        float pval = __expf(pacc[mi][jj]) * rv;
        Ps[ws_ * 32 + mi * 16 + q * 4 + jj][wt * 16 + r] = f2h(pval);
      }
    __syncthreads();
    // O += V * P : wave owns 32 c-rows
#pragma unroll
    for (int kk = 0; kk < 2; ++kk) {
#pragma unroll
      for (int mi = 0; mi < 2; ++mi) {
        half8 a = *(const half8*)&Vs[w * 32 + mi * 16 + r][kk * 32 + q * 8];
#pragma unroll
        for (int ni = 0; ni < 4; ++ni) {
          half8 b = *(const half8*)&Ps[ni * 16 + r][kk * 32 + q * 8];
          acc[mi][ni] = mfma16(a, b, acc[mi][ni]);
        }
      }
    }
    __syncthreads();
  }
  float* ob = outp + (size_t)n * C_DIM * S_DIM + (size_t)sb * 64;
#pragma unroll
  for (int mi = 0; mi < 2; ++mi)
#pragma unroll
    for (int ni = 0; ni < 4; ++ni)
#pragma unroll
      for (int jj = 0; jj < 4; ++jj) {
        int c = w * 32 + mi * 16 + q * 4 + jj;
        int s = ni * 16 + r;
        float* po = ob + (size_t)c * S_DIM + s;
        *po += acc[mi][ni][jj];
      }
}

extern "C" void kernel_launch(void* const* d_in, const int* in_sizes, int n_in,
                              void* d_out, int out_size, void* d_ws, size_t ws_size,
                              hipStream_t stream) {
  const float* x  = (const float*)d_in[0];
  const float* Wq = (const float*)d_in[1];
  const float* Wk = (const float*)d_in[2];
  const float* Wv = (const float*)d_in[3];
  const float* Wl = (const float*)d_in[4];
  float* out = (float*)d_out;
  char* base = (char*)d_ws;
  const size_t MB = 1024 * 1024;
  _Float16* xT = (_Float16*)(base);              // 16 MB
  _Float16* qT = (_Float16*)(base + 16 * MB);    // 16 MB
  _Float16* kT = (_Float16*)(base + 32 * MB);    // 16 MB
  _Float16* vv = (_Float16*)(base + 48 * MB);    // 16 MB
  _Float16* Wh = (_Float16*)(base + 64 * MB);    // 512 KB
  float* lsum  = (float*)(base + 64 * MB + 524288);  // 128 KB

  k_transpose<<<dim3(64, 4, N_B), dim3(256), 0, stream>>>(x, xT);
  k_wconv<<<dim3(64), dim3(256), 0, stream>>>(Wq, Wk, Wv, Wl, Wh);
  k_proj<<<dim3(64, 32), dim3(256), 0, stream>>>(xT, Wh, qT, kT, vv, out);
  k_rowsum<<<dim3(256), dim3(512), 0, stream>>>(qT, kT, lsum);
  k_attn<<<dim3(512), dim3(512), 0, stream>>>(qT, kT, vv, lsum, out);
}